// Round 1
// baseline (152.828 us; speedup 1.0000x reference)
//
#include <hip/hip_runtime.h>

// Fused: offset = conv3x3(x,w1)+b1 ; out = deform_conv(x, offset, w2)+b2
// x: (8,3,384,384) f32 ; w1: (18,3,3,3) ; b1: (18,) ; w2: (3,3,3,3) ; b2: (3,)
// out: (8,3,382,382) f32
// One thread per (b, ho, wo). 18 offsets recomputed inline (486 FMAs) to avoid
// materializing the 84MB offset tensor. Bilinear: always load clipped index,
// zero the corner weight when the UNclipped index is OOB (matches reference).

#define BB 8
#define CC 3
#define HH 384
#define WW 384
#define HO 382
#define WO 382
#define HW (HH * WW)

__global__ __launch_bounds__(256) void deform_fused_kernel(
    const float* __restrict__ x,
    const float* __restrict__ w1,
    const float* __restrict__ b1,
    const float* __restrict__ w2,
    const float* __restrict__ b2,
    float* __restrict__ out)
{
    __shared__ float s_w1[486];   // (18,27)
    __shared__ float s_b1[18];
    __shared__ float s_w2[81];    // (3,3,9) : o,c,k
    __shared__ float s_b2[3];

    for (int i = threadIdx.x; i < 486; i += 256) s_w1[i] = w1[i];
    for (int i = threadIdx.x; i < 81;  i += 256) s_w2[i] = w2[i];
    if (threadIdx.x < 18) s_b1[threadIdx.x] = b1[threadIdx.x];
    if (threadIdx.x < 3)  s_b2[threadIdx.x] = b2[threadIdx.x];
    __syncthreads();

    const int total = BB * HO * WO;
    int idx = blockIdx.x * 256 + threadIdx.x;
    if (idx >= total) return;

    const int wo = idx % WO;
    const int t  = idx / WO;
    const int ho = t % HO;
    const int b  = t / HO;

    const float* xb = x + (long)b * CC * HW;

    // 3x3x3 input neighborhood (reused by the offset conv)
    float xv[3][3][3];
#pragma unroll
    for (int c = 0; c < 3; ++c)
#pragma unroll
        for (int i = 0; i < 3; ++i)
#pragma unroll
            for (int j = 0; j < 3; ++j)
                xv[c][i][j] = xb[c * HW + (ho + i) * WW + (wo + j)];

    // 18 offset channels: off[2k]=dy_k, off[2k+1]=dx_k
    float off[18];
#pragma unroll
    for (int oc = 0; oc < 18; ++oc) {
        float a = s_b1[oc];
        const float* wp = s_w1 + oc * 27;
#pragma unroll
        for (int c = 0; c < 3; ++c)
#pragma unroll
            for (int i = 0; i < 3; ++i)
#pragma unroll
                for (int j = 0; j < 3; ++j)
                    a = fmaf(xv[c][i][j], wp[c * 9 + i * 3 + j], a);
        off[oc] = a;
    }

    float acc0 = s_b2[0], acc1 = s_b2[1], acc2 = s_b2[2];

    const float* xc0 = xb;
    const float* xc1 = xb + HW;
    const float* xc2 = xb + 2 * HW;

#pragma unroll
    for (int k = 0; k < 9; ++k) {
        const int kh = k / 3, kw = k % 3;
        const float py = (float)(ho + kh) + off[2 * k];
        const float px = (float)(wo + kw) + off[2 * k + 1];
        const float y0f = floorf(py);
        const float x0f = floorf(px);
        const float wy = py - y0f;
        const float wx = px - x0f;
        const int y0 = (int)y0f;
        const int x0 = (int)x0f;

        const float w00 = (1.f - wy) * (1.f - wx);
        const float w01 = (1.f - wy) * wx;
        const float w10 = wy * (1.f - wx);
        const float w11 = wy * wx;

        float v0 = 0.f, v1 = 0.f, v2 = 0.f;

#pragma unroll
        for (int corner = 0; corner < 4; ++corner) {
            const int yc = y0 + (corner >> 1);
            const int xc = x0 + (corner & 1);
            const float wt = (corner == 0) ? w00 : (corner == 1) ? w01
                           : (corner == 2) ? w10 : w11;
            const bool valid = (yc >= 0) & (yc <= HH - 1) & (xc >= 0) & (xc <= WW - 1);
            const int yi = min(max(yc, 0), HH - 1);
            const int xi = min(max(xc, 0), WW - 1);
            const float wv = valid ? wt : 0.f;
            const int base = yi * WW + xi;
            v0 = fmaf(wv, xc0[base], v0);
            v1 = fmaf(wv, xc1[base], v1);
            v2 = fmaf(wv, xc2[base], v2);
        }

        acc0 = fmaf(s_w2[0 * 27 + 0 * 9 + k], v0, acc0);
        acc0 = fmaf(s_w2[0 * 27 + 1 * 9 + k], v1, acc0);
        acc0 = fmaf(s_w2[0 * 27 + 2 * 9 + k], v2, acc0);
        acc1 = fmaf(s_w2[1 * 27 + 0 * 9 + k], v0, acc1);
        acc1 = fmaf(s_w2[1 * 27 + 1 * 9 + k], v1, acc1);
        acc1 = fmaf(s_w2[1 * 27 + 2 * 9 + k], v2, acc1);
        acc2 = fmaf(s_w2[2 * 27 + 0 * 9 + k], v0, acc2);
        acc2 = fmaf(s_w2[2 * 27 + 1 * 9 + k], v1, acc2);
        acc2 = fmaf(s_w2[2 * 27 + 2 * 9 + k], v2, acc2);
    }

    const int obase = (b * 3) * (HO * WO) + ho * WO + wo;
    out[obase]              = acc0;
    out[obase + HO * WO]     = acc1;
    out[obase + 2 * HO * WO] = acc2;
}

extern "C" void kernel_launch(void* const* d_in, const int* in_sizes, int n_in,
                              void* d_out, int out_size, void* d_ws, size_t ws_size,
                              hipStream_t stream) {
    const float* x  = (const float*)d_in[0];
    const float* w1 = (const float*)d_in[1];
    const float* b1 = (const float*)d_in[2];
    const float* w2 = (const float*)d_in[3];
    const float* b2 = (const float*)d_in[4];
    float* out = (float*)d_out;

    const int total = BB * HO * WO;           // 1,167,392
    const int blocks = (total + 255) / 256;   // 4561
    deform_fused_kernel<<<blocks, 256, 0, stream>>>(x, w1, b1, w2, b2, out);
}